// Round 9
// baseline (25.135 us; speedup 1.0000x reference)
//
#include <hip/hip_runtime.h>
#include <math.h>

// Problem constants (match reference setup_inputs)
constexpr int B = 16, H = 512, W = 512;
constexpr int NPIX = B * H * W;          // 4,194,304
constexpr int ROWS = 8;                  // pixel rows per block
constexpr int HALO = 2;                  // in-LDS window radius (tail is exact)
constexpr int LROWS = ROWS + 2 * HALO;   // 12 LDS rows -> 24 KB
constexpr int TPB = 512;                 // 8 waves per block
constexpr int NBLK = B * (H / ROWS);     // 1024 blocks -> 4 blocks/CU (32 waves)

#define ALPHA_C 0.5
#define BETA_C 0.5
#define SMOOTH_C 1e-06
#define BIGV 1000000.0f

__device__ inline float wave_reduce_f(float v) {
    #pragma unroll
    for (int off = 32; off > 0; off >>= 1)
        v += __shfl_down(v, off, 64);
    return v;
}

__device__ inline double wave_reduce_d(double v) {
    #pragma unroll
    for (int off = 32; off > 0; off >>= 1)
        v += __shfl_down(v, off, 64);
    return v;
}

// Exact nearest-opposite-class distance within one row, scanning outward
// from column c. Used only by the (very rare) tail path.
__device__ int row_nearest(const int* __restrict__ rowp, int c, bool oppOne) {
    for (int d = 0; d < W; ++d) {
        int l = c - d, r = c + d;
        if (l >= 0 && ((rowp[l] > 0) == oppOne)) return d;
        if (r <  W && ((rowp[r] > 0) == oppOne)) return d;
    }
    return 65535;
}

// ---------------------------------------------------------------------------
// Fused kernel. Each block owns an 8-row strip of one image (1024 blocks ->
// 4 blocks/CU = 32 waves/CU, full occupancy; LDS 24 KB).
// Prefetch: logits float4 pairs loaded BEFORE Phase A (latency hides under
//   the row scans).
// Phase A: 8 waves compute exact 1D row distances (wave-parallel max/min
//   scans, bitwise-identical to the reference recurrence) for rows
//   r0-2 .. r0+9, packed u16x2 into LDS. Out-of-image rows get the
//   0xFFFFFFFF sentinel (g=65535; g^2+rr < 2^32, can never win).
// Phase B: each wave handles 1 pixel row; each lane owns cols [lane*4,+4)
//   and [+256,+4) (16B/lane -> conflict-free LDS b128, coalesced float4).
//   Window candidates in u32 (mad+min_u32) — identical to the reference's
//   exact-integer f32 mins. Tail (best>9, rare) recomputes far rows from
//   tgt on demand — exact. Own-class EDT term is 0 (class = g1==0).
// Per-block f64 partials; finalize kernel reduces 1024 quads.
// ---------------------------------------------------------------------------
__global__ void __launch_bounds__(TPB, 8)
edt_fused_kernel(const float* __restrict__ logits,
                 const int* __restrict__ tgt,
                 double* __restrict__ partials) {
    __shared__ __align__(16) unsigned int gf[LROWS][W];   // 24 KB
    __shared__ double sh[8][4];

    const int lane = threadIdx.x & 63;
    const int wv   = threadIdx.x >> 6;          // 0..7
    const int b    = blockIdx.x >> 6;           // image index (64 strips/image)
    const int r0   = (blockIdx.x & 63) * ROWS;  // first pixel row (image-local)
    const int* timg = tgt + (size_t)b * H * W;
    const int c0 = lane * 4;                    // group A cols; group B at +256

    // ---- logits prefetch for this wave's Phase-B row ----
    const int i = r0 + wv;                      // pixel row (image-local)
    const size_t rowoff = (size_t)b * H * W + (size_t)i * W;
    const float4 plgA = *reinterpret_cast<const float4*>(logits + rowoff + c0);
    const float4 plgB = *reinterpret_cast<const float4*>(logits + rowoff + c0 + 256);

    const float NEG = -(BIGV + 1.0f);
    const float POS = (float)W + BIGV;
    const float wbase = (float)(lane * 8);

    // ---------------- Phase A: row scans into LDS ----------------
    for (int s = wv; s < LROWS; s += 8) {
        const int grow = r0 - HALO + s;
        if (grow < 0 || grow >= H) {
            const uint4 sent = make_uint4(~0u, ~0u, ~0u, ~0u);
            *reinterpret_cast<uint4*>(&gf[s][lane * 8])     = sent;
            *reinterpret_cast<uint4*>(&gf[s][lane * 8 + 4]) = sent;
            continue;
        }
        const int* rowp = timg + (size_t)grow * W;
        const int4 t0 = *reinterpret_cast<const int4*>(rowp + lane * 8);
        const int4 t1 = *reinterpret_cast<const int4*>(rowp + lane * 8 + 4);
        bool m[8] = { t0.x > 0, t0.y > 0, t0.z > 0, t0.w > 0,
                      t1.x > 0, t1.y > 0, t1.z > 0, t1.w > 0 };

        // lane-local last/first hit indices
        float la = NEG, lb = NEG, ra = POS, rb = POS;
        #pragma unroll
        for (int j = 0; j < 8; ++j) {
            float w = wbase + (float)j;
            if (m[j]) la = w; else lb = w;
        }
        #pragma unroll
        for (int j = 7; j >= 0; --j) {
            float w = wbase + (float)j;
            if (m[j]) ra = w; else rb = w;
        }

        // wave inclusive max-scan (prefix)
        float sa = la, sb = lb;
        #pragma unroll
        for (int off = 1; off < 64; off <<= 1) {
            float ua = __shfl_up(sa, off, 64);
            float ub = __shfl_up(sb, off, 64);
            if (lane >= off) { sa = fmaxf(sa, ua); sb = fmaxf(sb, ub); }
        }
        float carry_a = __shfl_up(sa, 1, 64); if (lane == 0) carry_a = NEG;
        float carry_b = __shfl_up(sb, 1, 64); if (lane == 0) carry_b = NEG;

        // wave inclusive min-scan (suffix)
        float ta = ra, tb = rb;
        #pragma unroll
        for (int off = 1; off < 64; off <<= 1) {
            float ua = __shfl_down(ta, off, 64);
            float ub = __shfl_down(tb, off, 64);
            if (lane < 64 - off) { ta = fminf(ta, ua); tb = fminf(tb, ub); }
        }
        float rcarry_a = __shfl_down(ta, 1, 64); if (lane == 63) rcarry_a = POS;
        float rcarry_b = __shfl_down(tb, 1, 64); if (lane == 63) rcarry_b = POS;

        // per-element distances
        float ga[8], gb[8];
        la = carry_a; lb = carry_b;
        #pragma unroll
        for (int j = 0; j < 8; ++j) {
            float w = wbase + (float)j;
            if (m[j]) la = w; else lb = w;
            ga[j] = w - la;
            gb[j] = w - lb;
        }
        ra = rcarry_a; rb = rcarry_b;
        #pragma unroll
        for (int j = 7; j >= 0; --j) {
            float w = wbase + (float)j;
            if (m[j]) ra = w; else rb = w;
            ga[j] = fminf(ga[j], ra - w);
            gb[j] = fminf(gb[j], rb - w);
        }

        unsigned int pk[8];
        #pragma unroll
        for (int j = 0; j < 8; ++j) {
            unsigned int ua = (unsigned int)fminf(ga[j], 65535.0f);  // dist to 1
            unsigned int ub = (unsigned int)fminf(gb[j], 65535.0f);  // dist to 0
            pk[j] = ua | (ub << 16);
        }
        *reinterpret_cast<uint4*>(&gf[s][lane * 8])     = make_uint4(pk[0], pk[1], pk[2], pk[3]);
        *reinterpret_cast<uint4*>(&gf[s][lane * 8 + 4]) = make_uint4(pk[4], pk[5], pk[6], pk[7]);
    }
    __syncthreads();

    // ---------------- Phase B: window search + loss (1 row/wave) ----------
    float acc_pd = 0.0f, acc_p = 0.0f, acc_t = 0.0f, acc_pt = 0.0f;
    const int ci = wv + HALO;         // this wave's LDS row

    const uint4 vA = *reinterpret_cast<const uint4*>(&gf[ci][c0]);
    const uint4 vB = *reinterpret_cast<const uint4*>(&gf[ci][c0 + 256]);

    const unsigned int va[8] = { vA.x, vA.y, vA.z, vA.w, vB.x, vB.y, vB.z, vB.w };
    const float xv[8] = { plgA.x, plgA.y, plgA.z, plgA.w,
                          plgB.x, plgB.y, plgB.z, plgB.w };

    unsigned int best[8], shf[8];
    #pragma unroll
    for (int k = 0; k < 8; ++k) {
        bool t = ((va[k] & 0xffffu) == 0u);     // g1==0 <=> target==1
        shf[k] = t ? 16u : 0u;                  // opposite-field shift
        unsigned int g = (va[k] >> shf[k]) & 0xffffu;
        best[k] = g * g;
    }

    #pragma unroll
    for (int r = 1; r <= HALO; ++r) {
        const unsigned int rr = (unsigned int)(r * r);
        const uint4 uA = *reinterpret_cast<const uint4*>(&gf[ci - r][c0]);
        const uint4 uB = *reinterpret_cast<const uint4*>(&gf[ci - r][c0 + 256]);
        const uint4 dA = *reinterpret_cast<const uint4*>(&gf[ci + r][c0]);
        const uint4 dB = *reinterpret_cast<const uint4*>(&gf[ci + r][c0 + 256]);
        const unsigned int au[8] = { uA.x, uA.y, uA.z, uA.w, uB.x, uB.y, uB.z, uB.w };
        const unsigned int ad[8] = { dA.x, dA.y, dA.z, dA.w, dB.x, dB.y, dB.z, dB.w };
        #pragma unroll
        for (int k = 0; k < 8; ++k) {
            unsigned int gu = (au[k] >> shf[k]) & 0xffffu;
            unsigned int gd = (ad[k] >> shf[k]) & 0xffffu;
            best[k] = min(best[k], gu * gu + rr);
            best[k] = min(best[k], gd * gd + rr);
        }
    }

    // exact tail fallback: r>HALO candidates are >= (HALO+1)^2, so they only
    // matter if best > (HALO+1)^2. Rare (edge rows mostly); exact when taken.
    #pragma unroll
    for (int k = 0; k < 8; ++k) {
        float bf = (float)best[k];
        if (bf > (float)((HALO + 1) * (HALO + 1))) {
            const int col = (k < 4) ? (c0 + k) : (c0 + 256 + k - 4);
            const bool oppOne = (shf[k] == 0u);    // opposite class is 1
            for (int r = HALO + 1; r < H; ++r) {
                const float rr = (float)(r * r);
                if (rr >= bf) break;
                const int ju = i - r, jd = i + r;
                if (ju >= 0) {
                    float g = (float)row_nearest(timg + (size_t)ju * W, col, oppOne);
                    bf = fminf(bf, fmaf(g, g, rr));
                }
                if (jd < H) {
                    float g = (float)row_nearest(timg + (size_t)jd * W, col, oppOne);
                    bf = fminf(bf, fmaf(g, g, rr));
                }
            }
        }
        const float dist = sqrtf(bf);               // own-class term is 0
        const float p = 1.0f / (1.0f + __expf(-xv[k]));
        const float tfv = shf[k] ? 1.0f : 0.0f;
        acc_pd += p * dist;
        acc_p  += p;
        acc_t  += tfv;
        acc_pt = fmaf(tfv, p, acc_pt);
    }

    const float w_pd = wave_reduce_f(acc_pd);
    const float w_p  = wave_reduce_f(acc_p);
    const float w_t  = wave_reduce_f(acc_t);
    const float w_pt = wave_reduce_f(acc_pt);

    if (lane == 0) {
        sh[wv][0] = (double)w_pd; sh[wv][1] = (double)w_p;
        sh[wv][2] = (double)w_t;  sh[wv][3] = (double)w_pt;
    }
    __syncthreads();
    if (threadIdx.x == 0) {
        double s0 = 0.0, s1 = 0.0, s2 = 0.0, s3 = 0.0;
        #pragma unroll
        for (int q = 0; q < 8; ++q) {
            s0 += sh[q][0]; s1 += sh[q][1]; s2 += sh[q][2]; s3 += sh[q][3];
        }
        double* outp = partials + (size_t)blockIdx.x * 4;
        outp[0] = s0; outp[1] = s1; outp[2] = s2; outp[3] = s3;
    }
}

// ---------------------------------------------------------------------------
// Finalize: reduce NBLK partial quads, compute scalar loss.
// ---------------------------------------------------------------------------
__global__ void finalize_kernel(const double* __restrict__ partials,
                                float* __restrict__ out) {
    double a0 = 0.0, a1 = 0.0, a2 = 0.0, a3 = 0.0;
    for (int j = threadIdx.x; j < NBLK; j += 256) {
        const double* p = partials + (size_t)j * 4;
        a0 += p[0]; a1 += p[1]; a2 += p[2]; a3 += p[3];
    }
    a0 = wave_reduce_d(a0);
    a1 = wave_reduce_d(a1);
    a2 = wave_reduce_d(a2);
    a3 = wave_reduce_d(a3);

    __shared__ double sh[4][4];
    const int wid = threadIdx.x >> 6, lane = threadIdx.x & 63;
    if (lane == 0) {
        sh[wid][0] = a0; sh[wid][1] = a1; sh[wid][2] = a2; sh[wid][3] = a3;
    }
    __syncthreads();
    if (threadIdx.x == 0) {
        double sum_pd = sh[0][0] + sh[1][0] + sh[2][0] + sh[3][0];
        double sum_p  = sh[0][1] + sh[1][1] + sh[2][1] + sh[3][1];
        double sum_t  = sh[0][2] + sh[1][2] + sh[2][2] + sh[3][2];
        double sum_pt = sh[0][3] + sh[1][3] + sh[2][3] + sh[3][3];

        double mean_pd = sum_pd / (double)NPIX;
        double loss_b = BETA_C * mean_pd;
        double dice = (2.0 * sum_pt + SMOOTH_C) / (sum_p + sum_t + SMOOTH_C);
        double loss_d = 1.0 - dice;
        out[0] = (float)(ALPHA_C * loss_d + BETA_C * loss_b);
    }
}

// ---------------------------------------------------------------------------
extern "C" void kernel_launch(void* const* d_in, const int* in_sizes, int n_in,
                              void* d_out, int out_size, void* d_ws, size_t ws_size,
                              hipStream_t stream) {
    const float* logits = (const float*)d_in[0];   // [16,1,512,512] f32
    const int* tgt      = (const int*)d_in[1];     // [16,1,512,512] i32 (0/1)
    float* out = (float*)d_out;                    // scalar

    // Workspace: double partials[NBLK][4] (32 KB)
    double* partials = (double*)d_ws;

    edt_fused_kernel<<<NBLK, TPB, 0, stream>>>(logits, tgt, partials);
    finalize_kernel<<<1, 256, 0, stream>>>(partials, out);
}

// Round 10
// 20.469 us; speedup vs baseline: 1.2280x; 1.2280x over previous
//
#include <hip/hip_runtime.h>
#include <math.h>

// Problem constants (match reference setup_inputs)
constexpr int B = 16, H = 512, W = 512;
constexpr int NPIX = B * H * W;          // 4,194,304
constexpr int ROWS = 16;                 // pixel rows per block
constexpr int HALO = 2;                  // in-LDS window radius (tail is exact)
constexpr int LROWS = ROWS + 2 * HALO;   // 20 LDS rows -> 40 KB
constexpr int TPB = 512;                 // 8 waves per block
constexpr int NBLK = B * (H / ROWS);     // 512 blocks

#define ALPHA_C 0.5
#define BETA_C 0.5
#define SMOOTH_C 1e-06
constexpr int NEG_I = -1000001;          // fwd no-hit carry: w - NEG = w+1000001
constexpr int POS_I = 1000512;           // bwd no-hit carry: POS - w = 1000512-w

__device__ inline float wave_reduce_f(float v) {
    #pragma unroll
    for (int off = 32; off > 0; off >>= 1)
        v += __shfl_down(v, off, 64);
    return v;
}

__device__ inline double wave_reduce_d(double v) {
    #pragma unroll
    for (int off = 32; off > 0; off >>= 1)
        v += __shfl_down(v, off, 64);
    return v;
}

// Exact nearest-opposite-class distance within one row, scanning outward
// from column c. Used only by the (very rare) tail path.
__device__ int row_nearest(const int* __restrict__ rowp, int c, bool oppOne) {
    for (int d = 0; d < W; ++d) {
        int l = c - d, r = c + d;
        if (l >= 0 && ((rowp[l] > 0) == oppOne)) return d;
        if (r <  W && ((rowp[r] > 0) == oppOne)) return d;
    }
    return 65535;
}

// ---------------------------------------------------------------------------
// Fused kernel. Each block owns a 16-row strip of one image.
// Phase A (ballot-based, O(1) shuffle depth): each lane owns 8 pixels and
//   builds an 8-bit class mask. The cross-lane carries (nearest hit before/
//   after the lane's chunk) come from __ballot + clz/ctz + ONE indexed
//   __shfl per field-direction — replacing the former 6-deep shuffle scans.
//   Distances are exact integers, identical to the reference recurrence
//   (fwd no-hit: w+1000001; bwd no-hit: 1000512-w), clamped to u16 and
//   packed (g1 | g0<<16) into LDS. Out-of-image rows get 0xFFFFFFFF
//   (g=65535; g^2+rr = 4294836229 < 2^32, can never win vs real hits).
// Phase B: each wave handles 2 pixel rows; each lane owns cols [lane*4,+4)
//   and [+256,+4). Window candidates in u32 (mad+min) — identical compares
//   to the reference's exact-integer f32 mins. Tail (best>9) recomputes far
//   rows from tgt on demand — exact. Own-class EDT term is 0 (class=g1==0).
// Per-block f64 partials; finalize kernel reduces 512 quads.
// ---------------------------------------------------------------------------
__global__ void __launch_bounds__(TPB, 8)
edt_fused_kernel(const float* __restrict__ logits,
                 const int* __restrict__ tgt,
                 double* __restrict__ partials) {
    __shared__ __align__(16) unsigned int gf[LROWS][W];   // 40 KB
    __shared__ double sh[8][4];

    const int lane = threadIdx.x & 63;
    const int wv   = threadIdx.x >> 6;          // 0..7
    const int b    = blockIdx.x >> 5;           // image index (32 strips/image)
    const int r0   = (blockIdx.x & 31) * ROWS;  // first pixel row (image-local)
    const int* timg = tgt + (size_t)b * H * W;
    const int c0 = lane * 4;                    // group A cols; group B at +256
    const int wb = lane * 8;                    // Phase-A chunk base column

    // ---- logits prefetch for both Phase-B rows (hides under Phase A) ----
    float4 plg[2][2];
    #pragma unroll
    for (int half = 0; half < 2; ++half) {
        const size_t rowoff = (size_t)b * H * W + (size_t)(r0 + wv + half * 8) * W;
        plg[half][0] = *reinterpret_cast<const float4*>(logits + rowoff + c0);
        plg[half][1] = *reinterpret_cast<const float4*>(logits + rowoff + c0 + 256);
    }

    // ---------------- Phase A: ballot-based row scans into LDS ----------
    for (int s = wv; s < LROWS; s += 8) {
        const int grow = r0 - HALO + s;
        if (grow < 0 || grow >= H) {
            const uint4 sent = make_uint4(~0u, ~0u, ~0u, ~0u);
            *reinterpret_cast<uint4*>(&gf[s][wb])     = sent;
            *reinterpret_cast<uint4*>(&gf[s][wb + 4]) = sent;
            continue;
        }
        const int* rowp = timg + (size_t)grow * W;
        const int4 t0 = *reinterpret_cast<const int4*>(rowp + wb);
        const int4 t1 = *reinterpret_cast<const int4*>(rowp + wb + 4);
        const unsigned int m1 =
              (unsigned int)(t0.x > 0)        | ((unsigned int)(t0.y > 0) << 1)
            | ((unsigned int)(t0.z > 0) << 2) | ((unsigned int)(t0.w > 0) << 3)
            | ((unsigned int)(t1.x > 0) << 4) | ((unsigned int)(t1.y > 0) << 5)
            | ((unsigned int)(t1.z > 0) << 6) | ((unsigned int)(t1.w > 0) << 7);
        const unsigned int m0 = m1 ^ 0xffu;

        const unsigned long long A1 = __ballot(m1 != 0u);
        const unsigned long long A0 = __ballot(m0 != 0u);

        // per-lane extreme hit positions (global cols; valid iff mask nonzero)
        const int last1  = wb + (31 - __clz(m1));
        const int last0  = wb + (31 - __clz(m0));
        const int first1 = wb + (__ffs((int)m1) - 1);
        const int first0 = wb + (__ffs((int)m0) - 1);

        // carries before this chunk (last hit in lower lanes)
        const unsigned long long below =
            (lane == 0) ? 0ull : (0xffffffffffffffffull >> (64 - lane));
        const unsigned long long p1 = A1 & below, p0 = A0 & below;
        int c1 = __shfl(last1, p1 ? (63 - (int)__builtin_clzll(p1)) : 0, 64);
        if (!p1) c1 = NEG_I;
        int cz = __shfl(last0, p0 ? (63 - (int)__builtin_clzll(p0)) : 0, 64);
        if (!p0) cz = NEG_I;

        // carries after this chunk (first hit in higher lanes)
        const unsigned long long above =
            (lane == 63) ? 0ull : (0xffffffffffffffffull << (lane + 1));
        const unsigned long long n1 = A1 & above, n0 = A0 & above;
        int e1 = __shfl(first1, n1 ? (int)__builtin_ctzll(n1) : 0, 64);
        if (!n1) e1 = POS_I;
        int ez = __shfl(first0, n0 ? (int)__builtin_ctzll(n0) : 0, 64);
        if (!n0) ez = POS_I;

        // per-element distances (exact integers)
        int ga[8], gb[8];
        int la = c1, lb = cz;
        #pragma unroll
        for (int j = 0; j < 8; ++j) {
            const int w = wb + j;
            if ((m1 >> j) & 1u) la = w; else lb = w;
            ga[j] = w - la;
            gb[j] = w - lb;
        }
        int ra = e1, rb = ez;
        #pragma unroll
        for (int j = 7; j >= 0; --j) {
            const int w = wb + j;
            if ((m1 >> j) & 1u) ra = w; else rb = w;
            ga[j] = min(ga[j], ra - w);
            gb[j] = min(gb[j], rb - w);
        }

        unsigned int pk[8];
        #pragma unroll
        for (int j = 0; j < 8; ++j) {
            const unsigned int ua = (unsigned int)min(ga[j], 65535);  // dist to 1
            const unsigned int ub = (unsigned int)min(gb[j], 65535);  // dist to 0
            pk[j] = ua | (ub << 16);
        }
        *reinterpret_cast<uint4*>(&gf[s][wb])     = make_uint4(pk[0], pk[1], pk[2], pk[3]);
        *reinterpret_cast<uint4*>(&gf[s][wb + 4]) = make_uint4(pk[4], pk[5], pk[6], pk[7]);
    }
    __syncthreads();

    // ---------------- Phase B: window search + loss (2 rows/wave) ----------
    float acc_pd = 0.0f, acc_p = 0.0f, acc_t = 0.0f, acc_pt = 0.0f;

    #pragma unroll
    for (int half = 0; half < 2; ++half) {
        const int i  = r0 + wv + half * 8;    // pixel row (image-local)
        const int ci = wv + half * 8 + HALO;  // its LDS row

        const float4 lgA = plg[half][0];
        const float4 lgB = plg[half][1];
        const uint4  vA  = *reinterpret_cast<const uint4*>(&gf[ci][c0]);
        const uint4  vB  = *reinterpret_cast<const uint4*>(&gf[ci][c0 + 256]);

        const unsigned int va[8] = { vA.x, vA.y, vA.z, vA.w, vB.x, vB.y, vB.z, vB.w };
        const float xv[8] = { lgA.x, lgA.y, lgA.z, lgA.w, lgB.x, lgB.y, lgB.z, lgB.w };

        unsigned int best[8], shf[8];
        #pragma unroll
        for (int k = 0; k < 8; ++k) {
            bool t = ((va[k] & 0xffffu) == 0u);     // g1==0 <=> target==1
            shf[k] = t ? 16u : 0u;                  // opposite-field shift
            unsigned int g = (va[k] >> shf[k]) & 0xffffu;
            best[k] = g * g;
        }

        #pragma unroll
        for (int r = 1; r <= HALO; ++r) {
            const unsigned int rr = (unsigned int)(r * r);
            const uint4 uA = *reinterpret_cast<const uint4*>(&gf[ci - r][c0]);
            const uint4 uB = *reinterpret_cast<const uint4*>(&gf[ci - r][c0 + 256]);
            const uint4 dA = *reinterpret_cast<const uint4*>(&gf[ci + r][c0]);
            const uint4 dB = *reinterpret_cast<const uint4*>(&gf[ci + r][c0 + 256]);
            const unsigned int au[8] = { uA.x, uA.y, uA.z, uA.w, uB.x, uB.y, uB.z, uB.w };
            const unsigned int ad[8] = { dA.x, dA.y, dA.z, dA.w, dB.x, dB.y, dB.z, dB.w };
            #pragma unroll
            for (int k = 0; k < 8; ++k) {
                unsigned int gu = (au[k] >> shf[k]) & 0xffffu;
                unsigned int gd = (ad[k] >> shf[k]) & 0xffffu;
                best[k] = min(best[k], gu * gu + rr);
                best[k] = min(best[k], gd * gd + rr);
            }
        }

        // exact tail fallback: r>HALO candidates are >= (HALO+1)^2, so they
        // only matter if best > (HALO+1)^2. P ~ 3e-8 per pixel.
        #pragma unroll
        for (int k = 0; k < 8; ++k) {
            float bf = (float)best[k];
            if (bf > (float)((HALO + 1) * (HALO + 1))) {
                const int col = (k < 4) ? (c0 + k) : (c0 + 256 + k - 4);
                const bool oppOne = (shf[k] == 0u);    // opposite class is 1
                for (int r = HALO + 1; r < H; ++r) {
                    const float rr = (float)(r * r);
                    if (rr >= bf) break;
                    const int ju = i - r, jd = i + r;
                    if (ju >= 0) {
                        float g = (float)row_nearest(timg + (size_t)ju * W, col, oppOne);
                        bf = fminf(bf, fmaf(g, g, rr));
                    }
                    if (jd < H) {
                        float g = (float)row_nearest(timg + (size_t)jd * W, col, oppOne);
                        bf = fminf(bf, fmaf(g, g, rr));
                    }
                }
            }
            const float dist = sqrtf(bf);               // own-class term is 0
            const float p = 1.0f / (1.0f + __expf(-xv[k]));
            const float tfv = shf[k] ? 1.0f : 0.0f;
            acc_pd += p * dist;
            acc_p  += p;
            acc_t  += tfv;
            acc_pt = fmaf(tfv, p, acc_pt);
        }
    }

    const float w_pd = wave_reduce_f(acc_pd);
    const float w_p  = wave_reduce_f(acc_p);
    const float w_t  = wave_reduce_f(acc_t);
    const float w_pt = wave_reduce_f(acc_pt);

    if (lane == 0) {
        sh[wv][0] = (double)w_pd; sh[wv][1] = (double)w_p;
        sh[wv][2] = (double)w_t;  sh[wv][3] = (double)w_pt;
    }
    __syncthreads();
    if (threadIdx.x == 0) {
        double s0 = 0.0, s1 = 0.0, s2 = 0.0, s3 = 0.0;
        #pragma unroll
        for (int q = 0; q < 8; ++q) {
            s0 += sh[q][0]; s1 += sh[q][1]; s2 += sh[q][2]; s3 += sh[q][3];
        }
        double* outp = partials + (size_t)blockIdx.x * 4;
        outp[0] = s0; outp[1] = s1; outp[2] = s2; outp[3] = s3;
    }
}

// ---------------------------------------------------------------------------
// Finalize: reduce NBLK partial quads, compute scalar loss.
// ---------------------------------------------------------------------------
__global__ void finalize_kernel(const double* __restrict__ partials,
                                float* __restrict__ out) {
    double a0 = 0.0, a1 = 0.0, a2 = 0.0, a3 = 0.0;
    for (int j = threadIdx.x; j < NBLK; j += 256) {
        const double* p = partials + (size_t)j * 4;
        a0 += p[0]; a1 += p[1]; a2 += p[2]; a3 += p[3];
    }
    a0 = wave_reduce_d(a0);
    a1 = wave_reduce_d(a1);
    a2 = wave_reduce_d(a2);
    a3 = wave_reduce_d(a3);

    __shared__ double sh[4][4];
    const int wid = threadIdx.x >> 6, lane = threadIdx.x & 63;
    if (lane == 0) {
        sh[wid][0] = a0; sh[wid][1] = a1; sh[wid][2] = a2; sh[wid][3] = a3;
    }
    __syncthreads();
    if (threadIdx.x == 0) {
        double sum_pd = sh[0][0] + sh[1][0] + sh[2][0] + sh[3][0];
        double sum_p  = sh[0][1] + sh[1][1] + sh[2][1] + sh[3][1];
        double sum_t  = sh[0][2] + sh[1][2] + sh[2][2] + sh[3][2];
        double sum_pt = sh[0][3] + sh[1][3] + sh[2][3] + sh[3][3];

        double mean_pd = sum_pd / (double)NPIX;
        double loss_b = BETA_C * mean_pd;
        double dice = (2.0 * sum_pt + SMOOTH_C) / (sum_p + sum_t + SMOOTH_C);
        double loss_d = 1.0 - dice;
        out[0] = (float)(ALPHA_C * loss_d + BETA_C * loss_b);
    }
}

// ---------------------------------------------------------------------------
extern "C" void kernel_launch(void* const* d_in, const int* in_sizes, int n_in,
                              void* d_out, int out_size, void* d_ws, size_t ws_size,
                              hipStream_t stream) {
    const float* logits = (const float*)d_in[0];   // [16,1,512,512] f32
    const int* tgt      = (const int*)d_in[1];     // [16,1,512,512] i32 (0/1)
    float* out = (float*)d_out;                    // scalar

    // Workspace: double partials[NBLK][4] (16 KB)
    double* partials = (double*)d_ws;

    edt_fused_kernel<<<NBLK, TPB, 0, stream>>>(logits, tgt, partials);
    finalize_kernel<<<1, 256, 0, stream>>>(partials, out);
}